// Round 2
// baseline (797.383 us; speedup 1.0000x reference)
//
#include <hip/hip_runtime.h>
#include <math.h>

// ---------------- degree (in-degree over dst) ----------------
__global__ void k_deg(const int* __restrict__ dst, int* __restrict__ deg, int E) {
    int i = blockIdx.x * blockDim.x + threadIdx.x;
    if (i < E) atomicAdd(&deg[dst[i]], 1);
}

// ---------------- single-block exclusive scan: deg -> row_off[0..n], cursor ----------------
__global__ __launch_bounds__(1024) void k_scan(const int* __restrict__ deg,
                                               int* __restrict__ row_off,
                                               int* __restrict__ cursor, int n) {
    __shared__ int part[1024];
    int t = threadIdx.x;
    int chunk = (n + 1023) / 1024;
    int lo = t * chunk, hi = min(n, lo + chunk);
    int s = 0;
    for (int i = lo; i < hi; ++i) s += deg[i];
    part[t] = s;
    __syncthreads();
    for (int off = 1; off < 1024; off <<= 1) {   // Hillis-Steele inclusive
        int v = (t >= off) ? part[t - off] : 0;
        __syncthreads();
        part[t] += v;
        __syncthreads();
    }
    int run = part[t] - s;                        // exclusive prefix of this chunk
    for (int i = lo; i < hi; ++i) {
        row_off[i] = run;
        cursor[i]  = run;
        run += deg[i];
    }
    if (t == 1023) row_off[n] = part[1023];
}

// ---------------- dinv + pre-scaled features xsc[i] = x[i]*dinv[i] ----------------
__global__ void k_dinvx(const int* __restrict__ deg, const float* __restrict__ x,
                        float* __restrict__ dinv, float2* __restrict__ xsc, int n) {
    int i = blockIdx.x * blockDim.x + threadIdx.x;
    if (i < n) {
        float di = rsqrtf((float)deg[i] + 1.0f);  // +1 self loop, always > 0
        dinv[i] = di;
        xsc[i] = make_float2(x[2 * i] * di, x[2 * i + 1] * di);
    }
}

// ---------------- CSR fill (counting sort by dst) ----------------
__global__ void k_fill(const int* __restrict__ src, const int* __restrict__ dst,
                       int* __restrict__ cursor, int* __restrict__ csr_src, int E) {
    int e = blockIdx.x * blockDim.x + threadIdx.x;
    if (e < E) {
        int pos = atomicAdd(&cursor[dst[e]], 1);
        csr_src[pos] = src[e];
    }
}

// ---------------- layer 1 fused: CSR-gather 2-dim xa, h1 = relu(xa@W1+b1),
// ----------------                m2 = (h1@W2)*dinv.  One wave per node. ----------------
__global__ __launch_bounds__(256) void k_layer1(
    const float2* __restrict__ xsc, const float* __restrict__ dinv,
    const int* __restrict__ row_off, const int* __restrict__ csr_src,
    const float* __restrict__ W1, const float* __restrict__ b1,
    const float* __restrict__ W2, float* __restrict__ m2, int n) {
    __shared__ __align__(16) float h1s[4][128];   // per-wave h1 broadcast buffer
    int tid = threadIdx.x;
    int wid = tid >> 6, lane = tid & 63;

    // W2 column for this lane lives in registers across the whole grid-stride loop
    float w2r[128];
#pragma unroll
    for (int k = 0; k < 128; ++k) w2r[k] = W2[k * 64 + lane];

    for (int base = blockIdx.x * 4; base < n; base += gridDim.x * 4) {
        int i = base + wid;
        bool valid = i < n;
        int r0 = 0, r1 = 0;
        float di = 0.f;
        float2 self = make_float2(0.f, 0.f);
        if (valid) {
            r0 = row_off[i]; r1 = row_off[i + 1];
            di = dinv[i];
            self = xsc[i];
        }
        float xa0 = 0.f, xa1 = 0.f;
        for (int j = r0 + lane; j < r1; j += 64) {  // gather pre-scaled neighbor features
            float2 v = xsc[csr_src[j]];
            xa0 += v.x; xa1 += v.y;
        }
#pragma unroll
        for (int off = 32; off; off >>= 1) {        // butterfly: all lanes get the sum
            xa0 += __shfl_xor(xa0, off);
            xa1 += __shfl_xor(xa1, off);
        }
        xa0 = (xa0 + self.x) * di;
        xa1 = (xa1 + self.y) * di;

        __syncthreads();                            // protect h1s vs previous iteration
        if (valid) {
            float h_lo = fmaxf(fmaf(xa1, W1[128 + lane], fmaf(xa0, W1[lane], b1[lane])), 0.f);
            float h_hi = fmaxf(fmaf(xa1, W1[192 + lane], fmaf(xa0, W1[64 + lane], b1[64 + lane])), 0.f);
            h1s[wid][lane]      = h_lo;
            h1s[wid][64 + lane] = h_hi;
        }
        __syncthreads();
        if (valid) {
            const float4* h4 = reinterpret_cast<const float4*>(h1s[wid]);
            float acc = 0.f;
#pragma unroll
            for (int k4 = 0; k4 < 32; ++k4) {       // broadcast b128 reads, reg-resident W2
                float4 h = h4[k4];
                acc = fmaf(h.x, w2r[4 * k4 + 0], acc);
                acc = fmaf(h.y, w2r[4 * k4 + 1], acc);
                acc = fmaf(h.z, w2r[4 * k4 + 2], acc);
                acc = fmaf(h.w, w2r[4 * k4 + 3], acc);
            }
            m2[(size_t)i * 64 + lane] = acc * di;   // pre-scaled by dinv[src]
        }
    }
}

// ---------------- layer 2 gather + full epilogue, one wave per node ----------------
__global__ __launch_bounds__(256) void k_l2out(
    const float* __restrict__ m2, const float* __restrict__ dinv,
    const int* __restrict__ row_off, const int* __restrict__ csr_src,
    const float* __restrict__ b2, const float* __restrict__ Wp,
    const float* __restrict__ bp, float* __restrict__ out, int n) {
    int tid = threadIdx.x;
    int wid = tid >> 6, lane = tid & 63;
    float b2l = b2[lane], wpl = Wp[lane], bp0 = bp[0];
    int i = blockIdx.x * 4 + wid;
    if (i >= n) return;
    int r0 = row_off[i], r1 = row_off[i + 1];
    float acc = m2[(size_t)i * 64 + lane];          // self-loop term
    for (int j = r0; j < r1; ++j) {
        int s = csr_src[j];
        acc += m2[(size_t)s * 64 + lane];           // coalesced 256B row gather (L3-resident)
    }
    float v = fmaxf(acc * dinv[i] + b2l, 0.f) * wpl;
#pragma unroll
    for (int off = 32; off; off >>= 1) v += __shfl_xor(v, off);
    if (lane == 0) out[i] = 1.f / (1.f + expf(-(v + bp0)));
}

extern "C" void kernel_launch(void* const* d_in, const int* in_sizes, int n_in,
                              void* d_out, int out_size, void* d_ws, size_t ws_size,
                              hipStream_t stream) {
    const float* x  = (const float*)d_in[0];
    const int*   ei = (const int*)d_in[1];   // [2, E] int32
    const float* W1 = (const float*)d_in[2];
    const float* b1 = (const float*)d_in[3];
    const float* W2 = (const float*)d_in[4];
    const float* b2 = (const float*)d_in[5];
    const float* Wp = (const float*)d_in[6];
    const float* bp = (const float*)d_in[7];
    float* out = (float*)d_out;

    int n = in_sizes[0] / 2;
    int E = in_sizes[1] / 2;
    const int* src = ei;
    const int* dst = ei + E;

    char* ws = (char*)d_ws;
    size_t off = 0;
    auto alloc = [&](size_t bytes) -> void* {
        void* p = ws + off;
        off += (bytes + 255) & ~(size_t)255;
        return p;
    };
    int*    deg     = (int*)alloc((size_t)n * 4);
    int*    row_off = (int*)alloc((size_t)(n + 1) * 4);
    int*    cursor  = (int*)alloc((size_t)n * 4);
    float*  dinv    = (float*)alloc((size_t)n * 4);
    float2* xsc     = (float2*)alloc((size_t)n * 8);
    int*    csr_src = (int*)alloc((size_t)E * 4);
    float*  m2      = (float*)alloc((size_t)n * 64 * 4);
    (void)ws_size;

    hipMemsetAsync(deg, 0, (size_t)n * 4, stream);
    k_deg  <<<(E + 255) / 256, 256, 0, stream>>>(dst, deg, E);
    k_scan <<<1, 1024, 0, stream>>>(deg, row_off, cursor, n);
    k_dinvx<<<(n + 255) / 256, 256, 0, stream>>>(deg, x, dinv, xsc, n);
    k_fill <<<(E + 255) / 256, 256, 0, stream>>>(src, dst, cursor, csr_src, E);
    k_layer1<<<2048, 256, 0, stream>>>(xsc, dinv, row_off, csr_src, W1, b1, W2, m2, n);
    k_l2out<<<(n + 3) / 4, 256, 0, stream>>>(m2, dinv, row_off, csr_src, b2, Wp, bp, out, n);
}

// Round 3
// 355.844 us; speedup vs baseline: 2.2408x; 2.2408x over previous
//
#include <hip/hip_runtime.h>
#include <math.h>

constexpr int SCAN_TPB = 256;
constexpr int SCAN_EPT = 8;                      // elements per thread
constexpr int SCAN_EPB = SCAN_TPB * SCAN_EPT;    // 2048 per block

// ---------------- degree (in-degree over dst) ----------------
__global__ void k_deg(const int* __restrict__ dst, int* __restrict__ deg, int E) {
    int i = blockIdx.x * blockDim.x + threadIdx.x;
    if (i < E) atomicAdd(&deg[dst[i]], 1);
}

// ---------------- scan phase A: per-block sums ----------------
__global__ __launch_bounds__(SCAN_TPB) void k_blocksum(const int* __restrict__ deg,
                                                       int* __restrict__ bsum, int n) {
    int t = threadIdx.x;
    int idx0 = blockIdx.x * SCAN_EPB + t * SCAN_EPT;
    int s = 0;
    if (idx0 + SCAN_EPT <= n) {
        const int4* p = reinterpret_cast<const int4*>(deg + idx0);
        int4 a = p[0], b = p[1];
        s = a.x + a.y + a.z + a.w + b.x + b.y + b.z + b.w;
    } else {
        for (int k = 0; k < SCAN_EPT; ++k) { int i = idx0 + k; if (i < n) s += deg[i]; }
    }
#pragma unroll
    for (int off = 32; off; off >>= 1) s += __shfl_xor(s, off);
    __shared__ int wsum[4];
    int lane = t & 63, wid = t >> 6;
    if (lane == 0) wsum[wid] = s;
    __syncthreads();
    if (t == 0) bsum[blockIdx.x] = wsum[0] + wsum[1] + wsum[2] + wsum[3];
}

// ---------------- scan phase B: exclusive-scan the block sums (tiny) ----------------
__global__ __launch_bounds__(256) void k_scanbsum(int* __restrict__ bsum,
                                                  int* __restrict__ row_off, int nb, int n) {
    int t = threadIdx.x, lane = t & 63, wid = t >> 6;
    __shared__ int wsum[4];
    int carry = 0;
    for (int base = 0; base < nb; base += 256) {
        int i = base + t;
        int v = (i < nb) ? bsum[i] : 0;
        int s = v;
#pragma unroll
        for (int off = 1; off < 64; off <<= 1) { int u = __shfl_up(s, off); if (lane >= off) s += u; }
        if (lane == 63) wsum[wid] = s;
        __syncthreads();
        int add = carry;
        for (int w = 0; w < wid; ++w) add += wsum[w];
        if (i < nb) bsum[i] = s - v + add;        // exclusive + carry
        carry += wsum[0] + wsum[1] + wsum[2] + wsum[3];
        __syncthreads();
    }
    if (t == 0) row_off[n] = carry;               // total edge count
}

// ---------------- scan phase C: final scan, write row_off + cursor ----------------
__global__ __launch_bounds__(SCAN_TPB) void k_scanfinal(const int* __restrict__ deg,
                                                        const int* __restrict__ bsum,
                                                        int* __restrict__ row_off,
                                                        int* __restrict__ cursor, int n) {
    int t = threadIdx.x, lane = t & 63, wid = t >> 6;
    int idx0 = blockIdx.x * SCAN_EPB + t * SCAN_EPT;
    int e[SCAN_EPT];
    bool full = (idx0 + SCAN_EPT <= n);
    if (full) {
        const int4* p = reinterpret_cast<const int4*>(deg + idx0);
        int4 a = p[0], b = p[1];
        e[0] = a.x; e[1] = a.y; e[2] = a.z; e[3] = a.w;
        e[4] = b.x; e[5] = b.y; e[6] = b.z; e[7] = b.w;
    } else {
        for (int k = 0; k < SCAN_EPT; ++k) { int i = idx0 + k; e[k] = (i < n) ? deg[i] : 0; }
    }
    int tsum = 0;
#pragma unroll
    for (int k = 0; k < SCAN_EPT; ++k) tsum += e[k];
    int s = tsum;
#pragma unroll
    for (int off = 1; off < 64; off <<= 1) { int u = __shfl_up(s, off); if (lane >= off) s += u; }
    __shared__ int wsum[4];
    if (lane == 63) wsum[wid] = s;
    __syncthreads();
    int add = bsum[blockIdx.x];
    for (int w = 0; w < wid; ++w) add += wsum[w];
    int run = s - tsum + add;                     // thread's exclusive prefix
    int o[SCAN_EPT];
#pragma unroll
    for (int k = 0; k < SCAN_EPT; ++k) { o[k] = run; run += e[k]; }
    if (full) {
        int4* ro = reinterpret_cast<int4*>(row_off + idx0);
        int4* cu = reinterpret_cast<int4*>(cursor + idx0);
        ro[0] = make_int4(o[0], o[1], o[2], o[3]);
        ro[1] = make_int4(o[4], o[5], o[6], o[7]);
        cu[0] = make_int4(o[0], o[1], o[2], o[3]);
        cu[1] = make_int4(o[4], o[5], o[6], o[7]);
    } else {
        for (int k = 0; k < SCAN_EPT; ++k) {
            int i = idx0 + k;
            if (i < n) { row_off[i] = o[k]; cursor[i] = o[k]; }
        }
    }
}

// ---------------- dinv + pre-scaled features xsc[i] = x[i]*dinv[i] ----------------
__global__ void k_dinvx(const int* __restrict__ deg, const float* __restrict__ x,
                        float* __restrict__ dinv, float2* __restrict__ xsc, int n) {
    int i = blockIdx.x * blockDim.x + threadIdx.x;
    if (i < n) {
        float di = rsqrtf((float)deg[i] + 1.0f);  // +1 self loop, always > 0
        dinv[i] = di;
        xsc[i] = make_float2(x[2 * i] * di, x[2 * i + 1] * di);
    }
}

// ---------------- CSR fill (counting sort by dst) ----------------
__global__ void k_fill(const int* __restrict__ src, const int* __restrict__ dst,
                       int* __restrict__ cursor, int* __restrict__ csr_src, int E) {
    int e = blockIdx.x * blockDim.x + threadIdx.x;
    if (e < E) {
        int pos = atomicAdd(&cursor[dst[e]], 1);
        csr_src[pos] = src[e];
    }
}

// ---------------- layer 1 fused: CSR-gather 2-dim xa, h1 = relu(xa@W1+b1),
// ----------------                m2 = (h1@W2)*dinv.  One wave per node. ----------------
__global__ __launch_bounds__(256) void k_layer1(
    const float2* __restrict__ xsc, const float* __restrict__ dinv,
    const int* __restrict__ row_off, const int* __restrict__ csr_src,
    const float* __restrict__ W1, const float* __restrict__ b1,
    const float* __restrict__ W2, float* __restrict__ m2, int n) {
    __shared__ __align__(16) float h1s[4][128];   // per-wave h1 broadcast buffer
    int tid = threadIdx.x;
    int wid = tid >> 6, lane = tid & 63;

    // W2 column for this lane lives in registers across the whole grid-stride loop
    float w2r[128];
#pragma unroll
    for (int k = 0; k < 128; ++k) w2r[k] = W2[k * 64 + lane];

    for (int base = blockIdx.x * 4; base < n; base += gridDim.x * 4) {
        int i = base + wid;
        bool valid = i < n;
        int r0 = 0, r1 = 0;
        float di = 0.f;
        float2 self = make_float2(0.f, 0.f);
        if (valid) {
            r0 = row_off[i]; r1 = row_off[i + 1];
            di = dinv[i];
            self = xsc[i];
        }
        float xa0 = 0.f, xa1 = 0.f;
        for (int j = r0 + lane; j < r1; j += 64) {  // gather pre-scaled neighbor features
            float2 v = xsc[csr_src[j]];
            xa0 += v.x; xa1 += v.y;
        }
#pragma unroll
        for (int off = 32; off; off >>= 1) {        // butterfly: all lanes get the sum
            xa0 += __shfl_xor(xa0, off);
            xa1 += __shfl_xor(xa1, off);
        }
        xa0 = (xa0 + self.x) * di;
        xa1 = (xa1 + self.y) * di;

        __syncthreads();                            // protect h1s vs previous iteration
        if (valid) {
            float h_lo = fmaxf(fmaf(xa1, W1[128 + lane], fmaf(xa0, W1[lane], b1[lane])), 0.f);
            float h_hi = fmaxf(fmaf(xa1, W1[192 + lane], fmaf(xa0, W1[64 + lane], b1[64 + lane])), 0.f);
            h1s[wid][lane]      = h_lo;
            h1s[wid][64 + lane] = h_hi;
        }
        __syncthreads();
        if (valid) {
            const float4* h4 = reinterpret_cast<const float4*>(h1s[wid]);
            float acc = 0.f;
#pragma unroll
            for (int k4 = 0; k4 < 32; ++k4) {       // broadcast b128 reads, reg-resident W2
                float4 h = h4[k4];
                acc = fmaf(h.x, w2r[4 * k4 + 0], acc);
                acc = fmaf(h.y, w2r[4 * k4 + 1], acc);
                acc = fmaf(h.z, w2r[4 * k4 + 2], acc);
                acc = fmaf(h.w, w2r[4 * k4 + 3], acc);
            }
            m2[(size_t)i * 64 + lane] = acc * di;   // pre-scaled by dinv[src]
        }
    }
}

// ---------------- layer 2 gather + full epilogue, one wave per node ----------------
__global__ __launch_bounds__(256) void k_l2out(
    const float* __restrict__ m2, const float* __restrict__ dinv,
    const int* __restrict__ row_off, const int* __restrict__ csr_src,
    const float* __restrict__ b2, const float* __restrict__ Wp,
    const float* __restrict__ bp, float* __restrict__ out, int n) {
    int tid = threadIdx.x;
    int wid = tid >> 6, lane = tid & 63;
    float b2l = b2[lane], wpl = Wp[lane], bp0 = bp[0];
    int i = blockIdx.x * 4 + wid;
    if (i >= n) return;
    int r0 = row_off[i], r1 = row_off[i + 1];
    float acc = m2[(size_t)i * 64 + lane];          // self-loop term
    for (int j = r0; j < r1; ++j) {
        int s = csr_src[j];
        acc += m2[(size_t)s * 64 + lane];           // coalesced 256B row gather (L3-resident)
    }
    float v = fmaxf(acc * dinv[i] + b2l, 0.f) * wpl;
#pragma unroll
    for (int off = 32; off; off >>= 1) v += __shfl_xor(v, off);
    if (lane == 0) out[i] = 1.f / (1.f + expf(-(v + bp0)));
}

extern "C" void kernel_launch(void* const* d_in, const int* in_sizes, int n_in,
                              void* d_out, int out_size, void* d_ws, size_t ws_size,
                              hipStream_t stream) {
    const float* x  = (const float*)d_in[0];
    const int*   ei = (const int*)d_in[1];   // [2, E] int32
    const float* W1 = (const float*)d_in[2];
    const float* b1 = (const float*)d_in[3];
    const float* W2 = (const float*)d_in[4];
    const float* b2 = (const float*)d_in[5];
    const float* Wp = (const float*)d_in[6];
    const float* bp = (const float*)d_in[7];
    float* out = (float*)d_out;

    int n = in_sizes[0] / 2;
    int E = in_sizes[1] / 2;
    const int* src = ei;
    const int* dst = ei + E;

    char* ws = (char*)d_ws;
    size_t off = 0;
    auto alloc = [&](size_t bytes) -> void* {
        void* p = ws + off;
        off += (bytes + 255) & ~(size_t)255;
        return p;
    };
    int nb = (n + SCAN_EPB - 1) / SCAN_EPB;
    int*    deg     = (int*)alloc((size_t)n * 4);
    int*    bsum    = (int*)alloc((size_t)nb * 4);
    int*    row_off = (int*)alloc((size_t)(n + 1) * 4);
    int*    cursor  = (int*)alloc((size_t)n * 4);
    float*  dinv    = (float*)alloc((size_t)n * 4);
    float2* xsc     = (float2*)alloc((size_t)n * 8);
    int*    csr_src = (int*)alloc((size_t)E * 4);
    float*  m2      = (float*)alloc((size_t)n * 64 * 4);
    (void)ws_size;

    hipMemsetAsync(deg, 0, (size_t)n * 4, stream);
    k_deg      <<<(E + 255) / 256, 256, 0, stream>>>(dst, deg, E);
    k_blocksum <<<nb, SCAN_TPB, 0, stream>>>(deg, bsum, n);
    k_scanbsum <<<1, 256, 0, stream>>>(bsum, row_off, nb, n);
    k_scanfinal<<<nb, SCAN_TPB, 0, stream>>>(deg, bsum, row_off, cursor, n);
    k_dinvx    <<<(n + 255) / 256, 256, 0, stream>>>(deg, x, dinv, xsc, n);
    k_fill     <<<(E + 255) / 256, 256, 0, stream>>>(src, dst, cursor, csr_src, E);
    k_layer1   <<<2048, 256, 0, stream>>>(xsc, dinv, row_off, csr_src, W1, b1, W2, m2, n);
    k_l2out    <<<(n + 3) / 4, 256, 0, stream>>>(m2, dinv, row_off, csr_src, b2, Wp, bp, out, n);
}